// Round 7
// baseline (271.215 us; speedup 1.0000x reference)
//
#include <hip/hip_runtime.h>

// SelfAttention: B=4, S=2048, D=1024, H=16, Hd=64. f32 in/out, bf16 MFMA inside.

#define LOG2E 1.4426950408889634f
#define QSCALE (0.125f * LOG2E)   // 1/sqrt(64) * log2(e), folded into Wq/bq

typedef __bf16 bf16x8 __attribute__((ext_vector_type(8)));
typedef float f32x4 __attribute__((ext_vector_type(4)));
typedef float f32x2 __attribute__((ext_vector_type(2)));
typedef unsigned short u16x4 __attribute__((ext_vector_type(4)));
typedef unsigned short u16x8 __attribute__((ext_vector_type(8)));
typedef unsigned int u32x4 __attribute__((ext_vector_type(4)));

__device__ __forceinline__ unsigned short f2bf(float f) {
  unsigned int u = __builtin_bit_cast(unsigned int, f);
  u += 0x7fffu + ((u >> 16) & 1u);   // RNE
  return (unsigned short)(u >> 16);
}

// single-instruction pack: bf16(a) low16, bf16(b) high16 (RNE). gfx950 only.
__device__ __forceinline__ unsigned int cvtpk(float a, float b) {
  unsigned int r;
  asm("v_cvt_pk_bf16_f32 %0, %1, %2" : "=v"(r) : "v"(a), "v"(b));
  return r;
}

typedef const __attribute__((address_space(1))) void* gptr_t;
typedef __attribute__((address_space(3))) void* lptr_t;
__device__ __forceinline__ void gload16(const void* g, void* l) {
  __builtin_amdgcn_global_load_lds((gptr_t)g, (lptr_t)l, 16, 0, 0);
}

// ---------------- merged convert kernel ----------------
__global__ __launch_bounds__(256) void k_cvt(const float* __restrict__ x,
                                             const float* __restrict__ Wq, const float* __restrict__ Wk,
                                             const float* __restrict__ Wv, const float* __restrict__ Wo,
                                             unsigned short* __restrict__ xb, unsigned short* __restrict__ Wb) {
  int gi = (blockIdx.x * 256 + threadIdx.x) * 4;
  if (gi < 8388608) {
    f32x4 v = *(const f32x4*)(x + gi);
    u16x4 o; o[0] = f2bf(v[0]); o[1] = f2bf(v[1]); o[2] = f2bf(v[2]); o[3] = f2bf(v[3]);
    *(u16x4*)(xb + gi) = o;
  } else {
    int i = gi - 8388608;
    int wsel = i >> 20;
    int loc = i & 1048575;
    const float* src = (wsel == 0) ? Wq : (wsel == 1) ? Wk : (wsel == 2) ? Wv : Wo;
    float sc = (wsel == 0) ? QSCALE : 1.0f;
    f32x4 v = *(const f32x4*)(src + loc);
    u16x4 o; o[0] = f2bf(v[0] * sc); o[1] = f2bf(v[1] * sc); o[2] = f2bf(v[2] * sc); o[3] = f2bf(v[3] * sc);
    *(u16x4*)(Wb + i) = o;
  }
}

// ---------------- QKV projection GEMM (r14: 256x256, z-fused, phase-interleaved) --
// r13 (128², 2-phase) measured 668 TF = the known m230-V0 structural ceiling
// (conflicts->0 and dbuf both null). r14 = the proven escape: BM=BN=256, BK=64,
// 8 waves (2Mx4N, 128x64/wave), 128KB dbuf LDS, ONE barrier per K-tile.
// Per K-tile: stage kt+1 (8 gloads) -> read B-frags + A-q0 -> 4 quadrant
// phases {issue A-q+1 ds_reads under 16 MFMAs; lgkm(0)+sched_barrier} ->
// vmcnt(0) (issued ~3 phases earlier => no stall) -> barrier.
// LDS swizzle: slot = chunk ^ (row&7); staging source pre-swizzled, reads
// apply same XOR; 8 lanes/slot uniform -> absorbed by b128's 8-phase => 0 conf.
// z fused: 384 blocks (32m x 4n x 3z), XCD-chunked 8x48.
__global__ __launch_bounds__(512, 2) void k_gemm_qkv(
    const unsigned short* __restrict__ xb, const unsigned short* __restrict__ Wb,
    const float* __restrict__ bq, const float* __restrict__ bk, const float* __restrict__ bv,
    unsigned short* __restrict__ Qb, unsigned short* __restrict__ Kb, unsigned short* __restrict__ Vtb) {
  __shared__ unsigned short As[2 * 16384];  // 64KB: dbuf x 256 rows x 64k
  __shared__ unsigned short Bs[2 * 16384];  // 64KB
  const int tid = threadIdx.x;              // 0..511
  const int lane = tid & 63;
  const int w = tid >> 6;                   // 0..7
  const int wm = w >> 2;                    // 0..1
  const int wn = w & 3;                     // 0..3
  const int lin = blockIdx.x;               // 0..383
  const int swz = (lin & 7) * 48 + (lin >> 3);  // bijective XCD chunking
  const int z = swz >> 7;
  const int t7 = swz & 127;
  const int m0 = (t7 >> 2) << 8;            // 0..7936
  const int n0 = (t7 & 3) << 8;             // 0..768
  const unsigned short* W = Wb + ((size_t)z << 20);

  // staging: thread owns LDS 16B slot (p*512+tid); row = p*64 + tid>>3,
  // pslot = tid&7, logical chunk c = pslot ^ (row&7) (p*64 == 0 mod 8)
  const int srow = tid >> 3;
  const int sc_ = (tid & 7) ^ (srow & 7);
  const unsigned short* pA = xb + (size_t)(m0 + srow) * 1024 + sc_ * 8;
  const unsigned short* pB = W + (size_t)(n0 + srow) * 1024 + sc_ * 8;
  unsigned short* dA = As + tid * 8;
  unsigned short* dB = Bs + tid * 8;

  // read offsets (elements): row*64 + ((chunk ^ (row&7))<<3); row&7 == fr&7
  const int fr = lane & 15;
  const int kq = lane >> 4;
  int aoff[2], boff[2];
#pragma unroll
  for (int ds = 0; ds < 2; ++ds) {
    const int ps = ((ds * 4 + kq) ^ (fr & 7)) << 3;
    aoff[ds] = (wm * 128 + fr) * 64 + ps;   // + q*2048 + i*1024 immediates
    boff[ds] = (wn * 64 + fr) * 64 + ps;    // + nt*1024 immediates
  }

  f32x4 zero4 = {0.f, 0.f, 0.f, 0.f};
  f32x4 acc[8][4];
#pragma unroll
  for (int i = 0; i < 8; ++i)
#pragma unroll
    for (int jj = 0; jj < 4; ++jj) acc[i][jj] = zero4;

  // prologue: stage kt=0 -> buf0
#pragma unroll
  for (int p = 0; p < 4; ++p) gload16(pA + p * 65536, dA + p * 4096);
#pragma unroll
  for (int p = 0; p < 4; ++p) gload16(pB + p * 65536, dB + p * 4096);
  pA += 64; pB += 64;
  __syncthreads();

  for (int kt = 0; kt < 16; ++kt) {
    const int bo = (kt & 1) << 14;   // current buf element offset
    const int so = bo ^ 16384;       // stage dest buf
    // stage kt+1 (kt=15 harmlessly over-reads into adjacent workspace)
#pragma unroll
    for (int p = 0; p < 4; ++p) gload16(pA + p * 65536, dA + so + p * 4096);
#pragma unroll
    for (int p = 0; p < 4; ++p) gload16(pB + p * 65536, dB + so + p * 4096);
    pA += 64; pB += 64;

    // B-frags (whole K-tile) + A-frags quadrant 0
    bf16x8 bfr[8];
#pragma unroll
    for (int nt = 0; nt < 4; ++nt)
#pragma unroll
      for (int ds = 0; ds < 2; ++ds)
        bfr[nt * 2 + ds] = *(const bf16x8*)&Bs[bo + boff[ds] + nt * 1024];
    bf16x8 af[2][4];
#pragma unroll
    for (int i = 0; i < 2; ++i)
#pragma unroll
      for (int ds = 0; ds < 2; ++ds)
        af[0][i * 2 + ds] = *(const bf16x8*)&As[bo + aoff[ds] + i * 1024];
    asm volatile("s_waitcnt lgkmcnt(0)" ::: "memory");
    __builtin_amdgcn_sched_barrier(0);

#pragma unroll
    for (int q = 0; q < 4; ++q) {
      if (q < 3) {  // issue next quadrant's A reads under this quadrant's MFMAs
#pragma unroll
        for (int i = 0; i < 2; ++i)
#pragma unroll
          for (int ds = 0; ds < 2; ++ds)
            af[(q + 1) & 1][i * 2 + ds] =
                *(const bf16x8*)&As[bo + aoff[ds] + (q + 1) * 2048 + i * 1024];
      }
      __builtin_amdgcn_s_setprio(1);
#pragma unroll
      for (int ds = 0; ds < 2; ++ds)
#pragma unroll
        for (int i = 0; i < 2; ++i)
#pragma unroll
          for (int nt = 0; nt < 4; ++nt)
            acc[q * 2 + i][nt] = __builtin_amdgcn_mfma_f32_16x16x32_bf16(
                af[q & 1][i * 2 + ds], bfr[nt * 2 + ds], acc[q * 2 + i][nt], 0, 0, 0);
      __builtin_amdgcn_s_setprio(0);
      if (q < 3) {
        asm volatile("s_waitcnt lgkmcnt(0)" ::: "memory");
        __builtin_amdgcn_sched_barrier(0);
      }
    }

    // kt+1 landed (issued ~3 phases ago); all waves' reads of buf[bo] done
    asm volatile("s_waitcnt vmcnt(0)" ::: "memory");
    __builtin_amdgcn_s_barrier();
  }

  const float* bias = (z == 0) ? bq : (z == 1) ? bk : bv;
  const float bsc = (z == 0) ? QSCALE : 1.0f;
  const int rg = kq << 2;
#pragma unroll
  for (int mt = 0; mt < 8; ++mt) {
    const int mb = m0 + wm * 128 + mt * 16 + rg;
    const int b = mb >> 11;
    const int s = mb & 2047;
#pragma unroll
    for (int nt = 0; nt < 4; ++nt) {
      const int n = n0 + wn * 64 + nt * 16 + fr;
      const float bvv = bias[n] * bsc;
      const int h = n >> 6;
      const int d = n & 63;
      if (z == 2) {
        u16x4 pk;
#pragma unroll
        for (int r = 0; r < 4; ++r) pk[r] = f2bf(acc[mt][nt][r] + bvv);
        const int pbase = (s & ~31) | ((s & 12) << 1) | ((s & 16) >> 2);
        *(u16x4*)&Vtb[(((size_t)(b * 16 + h) << 6) + d) * 2048 + pbase] = pk;
      } else {
        unsigned short* O = (z == 0) ? Qb : Kb;
#pragma unroll
        for (int r = 0; r < 4; ++r)
          O[(((size_t)(b * 16 + h) << 11) + s + r) * 64 + d] = f2bf(acc[mt][nt][r] + bvv);
      }
    }
  }
}

// ---------------- flash attention (S^T, no-max softmax, register P) ----------
// r12 (unchanged): 8 waves/512 thr, QBLK=256, 48KB LDS, 2 blocks/CU;
// V_j hidden under QK^T via vmcnt(2); K_{j+1} dbuf via vmcnt(0) at iter end;
// setprio around MFMA clusters.
__global__ __launch_bounds__(512, 4) void k_flash(
    const unsigned short* __restrict__ Qb, const unsigned short* __restrict__ Kb,
    const unsigned short* __restrict__ Vtb, unsigned short* __restrict__ Ctx) {
  __shared__ unsigned short Ks[2 * 128 * 64];  // 32KB double-buffered [key][64d], 3-bit chunk xor
  __shared__ unsigned short Vts[64 * 128];     // 16KB [d][128k_perm], 4-bit chunk xor
  const int tid = threadIdx.x;
  const int lane = tid & 63;
  const int wq = tid >> 6;           // 0..7
  const int fr = lane & 15;
  const int qd = lane >> 4;
  const int lin = blockIdx.x + (blockIdx.y << 3);        // 0..511
  const int swz = ((lin & 7) << 6) + (lin >> 3);         // chunk 64 per XCD
  const int bh = swz >> 3;                               // 0..63
  const int q0 = (swz & 7) << 8;                         // 0..1792
  const size_t hoff = (size_t)bh << 17;  // 2048*64
  const unsigned short* Qh = Qb + hoff + ((size_t)q0 << 6);

  // ---- hoisted staging addresses (advance by constant stride per j) ----
  const unsigned short* kg[2];
  const unsigned short* vg[2];
  unsigned short* kl[2];
  unsigned short* vl[2];
#pragma unroll
  for (int p = 0; p < 2; ++p) {
    int slot = p * 512 + tid;
    int kr = slot >> 3, ch = slot & 7;
    kg[p] = Kb + hoff + (size_t)kr * 64 + ((ch ^ (kr & 7)) << 3);
    kl[p] = Ks + slot * 8;
    int dr = slot >> 4, ch2 = slot & 15;
    vg[p] = Vtb + hoff + (size_t)dr * 2048 + ((ch2 ^ (dr & 15)) << 3);
    vl[p] = Vts + slot * 8;
  }

  // ---- slim LDS read base offsets (kt/dt terms fold to ds_read immediates) ----
  int kbase[2];
#pragma unroll
  for (int ds = 0; ds < 2; ++ds)
    kbase[ds] = fr * 64 + (((ds * 4 + qd) ^ (fr & 7)) << 3);
  int vbase[4];
#pragma unroll
  for (int ks = 0; ks < 4; ++ks)
    vbase[ks] = fr * 128 + (((ks * 4 + qd) ^ fr) << 3);

  // Q fragments: B[n=query][k=d]; row = wq*32+qt*16+fr, d = ds*32+qd*8..+7
  bf16x8 qf[2][2];
#pragma unroll
  for (int qt = 0; qt < 2; ++qt)
#pragma unroll
    for (int ds = 0; ds < 2; ++ds)
      qf[qt][ds] = *(const bf16x8*)&Qh[(wq * 32 + qt * 16 + fr) * 64 + ds * 32 + qd * 8];

  f32x4 zero4 = {0.f, 0.f, 0.f, 0.f};
  f32x4 o_acc[2][4];
  f32x2 l2[2] = {{0.f, 0.f}, {0.f, 0.f}};
#pragma unroll
  for (int mt = 0; mt < 2; ++mt)
#pragma unroll
    for (int dt = 0; dt < 4; ++dt) o_acc[mt][dt] = zero4;

  // ---- prologue: stage K_0 into buf0, full drain ----
#pragma unroll
  for (int p = 0; p < 2; ++p) gload16(kg[p], kl[p]);
#pragma unroll
  for (int p = 0; p < 2; ++p) kg[p] += 128 * 64;  // -> K_1
  __syncthreads();  // vmcnt(0) + barrier: K_0 visible

  int curoff = 0;  // element offset of current K buffer (0 or 8192)
  for (int j = 0; j < 16; ++j) {
#pragma unroll
    for (int p = 0; p < 2; ++p) gload16(vg[p], vl[p]);
#pragma unroll
    for (int p = 0; p < 2; ++p) gload16(kg[p], kl[p] + (curoff ^ 8192));
#pragma unroll
    for (int p = 0; p < 2; ++p) { kg[p] += 128 * 64; vg[p] += 128; }

    // ---- fused S^T = K·Q^T -> exp2 -> l-sum -> bf16 pack, per key-pair ----
    const unsigned short* Kc = Ks + curoff;
    u32x4 pfw[2][4];
#pragma unroll
    for (int ks = 0; ks < 4; ++ks) {
      f32x4 st0[2], st1[2];  // [qt] for kt=2ks, 2ks+1
      st0[0] = zero4; st0[1] = zero4; st1[0] = zero4; st1[1] = zero4;
      __builtin_amdgcn_s_setprio(1);
#pragma unroll
      for (int ds = 0; ds < 2; ++ds) {
        bf16x8 kf0 = *(const bf16x8*)&Kc[kbase[ds] + (2 * ks) * 1024];
        bf16x8 kf1 = *(const bf16x8*)&Kc[kbase[ds] + (2 * ks + 1) * 1024];
        st0[0] = __builtin_amdgcn_mfma_f32_16x16x32_bf16(kf0, qf[0][ds], st0[0], 0, 0, 0);
        st0[1] = __builtin_amdgcn_mfma_f32_16x16x32_bf16(kf0, qf[1][ds], st0[1], 0, 0, 0);
        st1[0] = __builtin_amdgcn_mfma_f32_16x16x32_bf16(kf1, qf[0][ds], st1[0], 0, 0, 0);
        st1[1] = __builtin_amdgcn_mfma_f32_16x16x32_bf16(kf1, qf[1][ds], st1[1], 0, 0, 0);
      }
      __builtin_amdgcn_s_setprio(0);
#pragma unroll
      for (int mt = 0; mt < 2; ++mt) {
#pragma unroll
        for (int r = 0; r < 4; ++r) {
          st0[mt][r] = __builtin_amdgcn_exp2f(st0[mt][r]);
          st1[mt][r] = __builtin_amdgcn_exp2f(st1[mt][r]);
        }
        f32x2 s01 = {st0[mt][0], st0[mt][1]};
        f32x2 s23 = {st0[mt][2], st0[mt][3]};
        f32x2 t01 = {st1[mt][0], st1[mt][1]};
        f32x2 t23 = {st1[mt][2], st1[mt][3]};
        l2[mt] += (s01 + s23) + (t01 + t23);
        u32x4 pk;
        pk[0] = cvtpk(st0[mt][0], st0[mt][1]);
        pk[1] = cvtpk(st0[mt][2], st0[mt][3]);
        pk[2] = cvtpk(st1[mt][0], st1[mt][1]);
        pk[3] = cvtpk(st1[mt][2], st1[mt][3]);
        pfw[mt][ks] = pk;
      }
    }

    // V_j done (oldest 2); K_{j+1} may still be in flight
    asm volatile("s_waitcnt vmcnt(2)" ::: "memory");
    __builtin_amdgcn_s_barrier();

    // ---- O += P · V : A-fragments from packed regs (permuted-key order) ----
    __builtin_amdgcn_s_setprio(1);
#pragma unroll
    for (int ks = 0; ks < 4; ++ks) {
      bf16x8 pf0 = __builtin_bit_cast(bf16x8, pfw[0][ks]);
      bf16x8 pf1 = __builtin_bit_cast(bf16x8, pfw[1][ks]);
#pragma unroll
      for (int dt = 0; dt < 4; ++dt) {
        bf16x8 vf = *(const bf16x8*)&Vts[vbase[ks] + dt * 2048];
        o_acc[0][dt] = __builtin_amdgcn_mfma_f32_16x16x32_bf16(pf0, vf, o_acc[0][dt], 0, 0, 0);
        o_acc[1][dt] = __builtin_amdgcn_mfma_f32_16x16x32_bf16(pf1, vf, o_acc[1][dt], 0, 0, 0);
      }
    }
    __builtin_amdgcn_s_setprio(0);

    // K_{j+1} landed; all waves' Vts reads done -> safe to restage next iter
    asm volatile("s_waitcnt vmcnt(0)" ::: "memory");
    __builtin_amdgcn_s_barrier();
    curoff ^= 8192;
  }

  // reduce l across the 4 lanes sharing each query (fr), once
  float l_red[2];
#pragma unroll
  for (int mt = 0; mt < 2; ++mt) {
    float lv = l2[mt][0] + l2[mt][1];
    lv += __shfl_xor(lv, 16);
    lv += __shfl_xor(lv, 32);
    l_red[mt] = lv;
  }

  // epilogue: normalize, write context [b][s][h*64+d] bf16
  const int b = bh >> 4;
  const int h = bh & 15;
#pragma unroll
  for (int mt = 0; mt < 2; ++mt) {
#pragma unroll
    for (int r = 0; r < 4; ++r) {
      float lv = __shfl(l_red[mt], qd * 4 + r);
      float rl = 1.0f / lv;
      int s = q0 + wq * 32 + mt * 16 + qd * 4 + r;
      size_t base = (((size_t)b * 2048 + s) << 10) + (h << 6);
#pragma unroll
      for (int dt = 0; dt < 4; ++dt) Ctx[base + dt * 16 + fr] = f2bf(o_acc[mt][dt][r] * rl);
    }
  }
}

// ---------------- output projection GEMM (f32 out) ----------------
// r13 (unchanged): dbuf pipeline + paired-row XOR swizzle.
__global__ __launch_bounds__(256, 3) void k_gemm_out(
    const unsigned short* __restrict__ Ctx, const unsigned short* __restrict__ Wo,
    const float* __restrict__ bo, float* __restrict__ out) {
  __shared__ unsigned short As[2 * 4096];
  __shared__ unsigned short Bs[2 * 4096];
  const int tid = threadIdx.x;
  const int lane = tid & 63;
  const int w = tid >> 6;
  const int wm = w & 1;
  const int wn = w >> 1;
  const int lin = blockIdx.x + (blockIdx.y << 3);
  const int swz = ((lin & 7) << 6) + (lin >> 3);
  const int m0 = (swz >> 3) << 7;
  const int n0 = (swz & 7) << 7;

  const int sR = tid >> 3;
  const int sc_ = (tid & 7) ^ (sR & 7);
  const int mrow0 = 2 * sR + (sc_ >> 2);
  const int kc0 = (sc_ & 3) << 3;
  const unsigned short* srcA = Ctx + (size_t)(m0 + mrow0) * 1024 + kc0;
  const unsigned short* srcB = Wo + (size_t)(n0 + mrow0) * 1024 + kc0;
  unsigned short* dstA = As + tid * 8;
  unsigned short* dstB = Bs + tid * 8;

  const int fr = lane & 15;
  const int kq = lane >> 4;
  int aoff[4], boff[4];
#pragma unroll
  for (int t = 0; t < 4; ++t) {
    int ra = wm * 64 + t * 16 + fr;
    aoff[t] = ((ra >> 1) << 6) + (((((ra & 1) << 2) + kq) ^ ((ra >> 1) & 7)) << 3);
    int rb = wn * 64 + t * 16 + fr;
    boff[t] = ((rb >> 1) << 6) + (((((rb & 1) << 2) + kq) ^ ((rb >> 1) & 7)) << 3);
  }

  f32x4 zero4 = {0.f, 0.f, 0.f, 0.f};
  f32x4 acc[4][4];
#pragma unroll
  for (int i = 0; i < 4; ++i)
#pragma unroll
    for (int jj = 0; jj < 4; ++jj) acc[i][jj] = zero4;

  gload16(srcA, dstA);
  gload16(srcA + 65536, dstA + 2048);
  gload16(srcB, dstB);
  gload16(srcB + 65536, dstB + 2048);

  int cur = 0;
  for (int kt = 0; kt < 32; ++kt) {
    const int kon = ((kt + 1) & 31) << 5;
    const int soff = (cur ^ 1) << 12;
    gload16(srcA + kon, dstA + soff);
    gload16(srcA + 65536 + kon, dstA + soff + 2048);
    gload16(srcB + kon, dstB + soff);
    gload16(srcB + 65536 + kon, dstB + soff + 2048);

    asm volatile("s_waitcnt vmcnt(4)" ::: "memory");
    __builtin_amdgcn_s_barrier();

    const unsigned short* Ac = As + (cur << 12);
    const unsigned short* Bc = Bs + (cur << 12);
    bf16x8 af[4], bfr[4];
#pragma unroll
    for (int mt = 0; mt < 4; ++mt) af[mt] = *(const bf16x8*)&Ac[aoff[mt]];
#pragma unroll
    for (int nt = 0; nt < 4; ++nt) bfr[nt] = *(const bf16x8*)&Bc[boff[nt]];

    asm volatile("s_waitcnt lgkmcnt(0)" ::: "memory");
    __builtin_amdgcn_s_barrier();

    __builtin_amdgcn_s_setprio(1);
#pragma unroll
    for (int mt = 0; mt < 4; ++mt)
#pragma unroll
      for (int nt = 0; nt < 4; ++nt)
        acc[mt][nt] = __builtin_amdgcn_mfma_f32_16x16x32_bf16(af[mt], bfr[nt], acc[mt][nt], 0, 0, 0);
    __builtin_amdgcn_s_setprio(0);
    cur ^= 1;
  }

  const int rg = kq << 2;
#pragma unroll
  for (int mt = 0; mt < 4; ++mt) {
    const int mb = m0 + wm * 64 + mt * 16 + rg;
#pragma unroll
    for (int nt = 0; nt < 4; ++nt) {
      const int n = n0 + wn * 64 + nt * 16 + fr;
      const float bvv = bo[n];
#pragma unroll
      for (int r = 0; r < 4; ++r)
        out[(size_t)(mb + r) * 1024 + n] = acc[mt][nt][r] + bvv;
    }
  }
}

// ---------------- host ----------------
extern "C" void kernel_launch(void* const* d_in, const int* in_sizes, int n_in,
                              void* d_out, int out_size, void* d_ws, size_t ws_size,
                              hipStream_t stream) {
  (void)in_sizes; (void)n_in; (void)out_size; (void)ws_size;
  const float* x = (const float*)d_in[0];
  const float* Wq = (const float*)d_in[1];
  const float* bq = (const float*)d_in[2];
  const float* Wk = (const float*)d_in[3];
  const float* bk = (const float*)d_in[4];
  const float* Wv = (const float*)d_in[5];
  const float* bv = (const float*)d_in[6];
  const float* Wo = (const float*)d_in[7];
  const float* bo = (const float*)d_in[8];
  float* out = (float*)d_out;

  unsigned short* xb = (unsigned short*)d_ws;  // 8388608 el
  unsigned short* Wb = xb + 8388608;           // 4194304 el (q,k,v,o)
  unsigned short* Qb = Wb + 4194304;           // [b,h,s,d]
  unsigned short* Kb = Qb + 8388608;           // [b,h,s,d]
  unsigned short* Vtb = Kb + 8388608;          // [b,h,d,s_perm]
  unsigned short* Ctx = xb;                    // reuse xb (dead after k_gemm_qkv)

  k_cvt<<<12288, 256, 0, stream>>>(x, Wq, Wk, Wv, Wo, xb, Wb);
  k_gemm_qkv<<<384, 512, 0, stream>>>(xb, Wb, bq, bk, bv, Qb, Kb, Vtb);
  k_flash<<<dim3(8, 64), 512, 0, stream>>>(Qb, Kb, Vtb, Ctx);
  k_gemm_out<<<dim3(8, 64), 256, 0, stream>>>(Ctx, Wb + 3 * 1048576, bo, out);
}

// Round 8
// 261.145 us; speedup vs baseline: 1.0386x; 1.0386x over previous
//
#include <hip/hip_runtime.h>

// SelfAttention: B=4, S=2048, D=1024, H=16, Hd=64. f32 in/out, bf16 MFMA inside.

#define LOG2E 1.4426950408889634f
#define QSCALE (0.125f * LOG2E)   // 1/sqrt(64) * log2(e), folded into Wq/bq

typedef __bf16 bf16x8 __attribute__((ext_vector_type(8)));
typedef float f32x4 __attribute__((ext_vector_type(4)));
typedef float f32x2 __attribute__((ext_vector_type(2)));
typedef unsigned short u16x4 __attribute__((ext_vector_type(4)));
typedef unsigned short u16x8 __attribute__((ext_vector_type(8)));
typedef unsigned int u32x4 __attribute__((ext_vector_type(4)));

__device__ __forceinline__ unsigned short f2bf(float f) {
  unsigned int u = __builtin_bit_cast(unsigned int, f);
  u += 0x7fffu + ((u >> 16) & 1u);   // RNE
  return (unsigned short)(u >> 16);
}

// single-instruction pack: bf16(a) low16, bf16(b) high16 (RNE). gfx950 only.
__device__ __forceinline__ unsigned int cvtpk(float a, float b) {
  unsigned int r;
  asm("v_cvt_pk_bf16_f32 %0, %1, %2" : "=v"(r) : "v"(a), "v"(b));
  return r;
}

typedef const __attribute__((address_space(1))) void* gptr_t;
typedef __attribute__((address_space(3))) void* lptr_t;
__device__ __forceinline__ void gload16(const void* g, void* l) {
  __builtin_amdgcn_global_load_lds((gptr_t)g, (lptr_t)l, 16, 0, 0);
}

// ---------------- merged convert kernel ----------------
__global__ __launch_bounds__(256) void k_cvt(const float* __restrict__ x,
                                             const float* __restrict__ Wq, const float* __restrict__ Wk,
                                             const float* __restrict__ Wv, const float* __restrict__ Wo,
                                             unsigned short* __restrict__ xb, unsigned short* __restrict__ Wb) {
  int gi = (blockIdx.x * 256 + threadIdx.x) * 4;
  if (gi < 8388608) {
    f32x4 v = *(const f32x4*)(x + gi);
    u16x4 o; o[0] = f2bf(v[0]); o[1] = f2bf(v[1]); o[2] = f2bf(v[2]); o[3] = f2bf(v[3]);
    *(u16x4*)(xb + gi) = o;
  } else {
    int i = gi - 8388608;
    int wsel = i >> 20;
    int loc = i & 1048575;
    const float* src = (wsel == 0) ? Wq : (wsel == 1) ? Wk : (wsel == 2) ? Wv : Wo;
    float sc = (wsel == 0) ? QSCALE : 1.0f;
    f32x4 v = *(const f32x4*)(src + loc);
    u16x4 o; o[0] = f2bf(v[0] * sc); o[1] = f2bf(v[1] * sc); o[2] = f2bf(v[2] * sc); o[3] = f2bf(v[3] * sc);
    *(u16x4*)(Wb + i) = o;
  }
}

// ---------------- QKV projection GEMM (r13 structure, reverted from r14) -----
// r14's 256x256 1-block/CU rewrite regressed (77->100us: vmcnt(0)-per-K-tile
// drain with no co-resident block + 1.5-round grid). r13: 128x128, 2-phase dbuf
// pipeline, paired-row XOR swizzle (0 conflicts), 3 blocks/CU -- measured 77us
// = the known 2-phase structural ceiling (~670 TF).
__global__ __launch_bounds__(256, 3) void k_gemm_qkv(
    const unsigned short* __restrict__ xb, const unsigned short* __restrict__ Wb,
    const float* __restrict__ bq, const float* __restrict__ bk, const float* __restrict__ bv,
    unsigned short* __restrict__ Qb, unsigned short* __restrict__ Kb, unsigned short* __restrict__ Vtb) {
  __shared__ unsigned short As[2 * 4096];  // 16KB: 2 bufs x 64 rows x 128B (paired-row swz)
  __shared__ unsigned short Bs[2 * 4096];
  const int tid = threadIdx.x;
  const int lane = tid & 63;
  const int w = tid >> 6;
  const int wm = w & 1;
  const int wn = w >> 1;
  const int lin = blockIdx.x + (blockIdx.y << 3) + (blockIdx.z << 9);
  const int swz = (lin & 7) * 192 + (lin >> 3);
  const int z = swz >> 9;
  const int m0 = ((swz >> 3) & 63) << 7;
  const int n0 = (swz & 7) << 7;
  const unsigned short* W = Wb + ((size_t)z << 20);

  const int sR = tid >> 3;
  const int sc_ = (tid & 7) ^ (sR & 7);
  const int mrow0 = 2 * sR + (sc_ >> 2);
  const int kc0 = (sc_ & 3) << 3;
  const unsigned short* srcA = xb + (size_t)(m0 + mrow0) * 1024 + kc0;
  const unsigned short* srcB = W + (size_t)(n0 + mrow0) * 1024 + kc0;
  unsigned short* dstA = As + tid * 8;
  unsigned short* dstB = Bs + tid * 8;

  const int fr = lane & 15;
  const int kq = lane >> 4;
  int aoff[4], boff[4];
#pragma unroll
  for (int t = 0; t < 4; ++t) {
    int ra = wm * 64 + t * 16 + fr;
    aoff[t] = ((ra >> 1) << 6) + (((((ra & 1) << 2) + kq) ^ ((ra >> 1) & 7)) << 3);
    int rb = wn * 64 + t * 16 + fr;
    boff[t] = ((rb >> 1) << 6) + (((((rb & 1) << 2) + kq) ^ ((rb >> 1) & 7)) << 3);
  }

  f32x4 zero4 = {0.f, 0.f, 0.f, 0.f};
  f32x4 acc[4][4];
#pragma unroll
  for (int i = 0; i < 4; ++i)
#pragma unroll
    for (int jj = 0; jj < 4; ++jj) acc[i][jj] = zero4;

  gload16(srcA, dstA);
  gload16(srcA + 65536, dstA + 2048);
  gload16(srcB, dstB);
  gload16(srcB + 65536, dstB + 2048);

  int cur = 0;
  for (int kt = 0; kt < 32; ++kt) {
    const int kon = ((kt + 1) & 31) << 5;
    const int soff = (cur ^ 1) << 12;
    gload16(srcA + kon, dstA + soff);
    gload16(srcA + 65536 + kon, dstA + soff + 2048);
    gload16(srcB + kon, dstB + soff);
    gload16(srcB + 65536 + kon, dstB + soff + 2048);

    asm volatile("s_waitcnt vmcnt(4)" ::: "memory");
    __builtin_amdgcn_s_barrier();

    const unsigned short* Ac = As + (cur << 12);
    const unsigned short* Bc = Bs + (cur << 12);
    bf16x8 af[4], bfr[4];
#pragma unroll
    for (int mt = 0; mt < 4; ++mt) af[mt] = *(const bf16x8*)&Ac[aoff[mt]];
#pragma unroll
    for (int nt = 0; nt < 4; ++nt) bfr[nt] = *(const bf16x8*)&Bc[boff[nt]];

    asm volatile("s_waitcnt lgkmcnt(0)" ::: "memory");
    __builtin_amdgcn_s_barrier();

    __builtin_amdgcn_s_setprio(1);
#pragma unroll
    for (int mt = 0; mt < 4; ++mt)
#pragma unroll
      for (int nt = 0; nt < 4; ++nt)
        acc[mt][nt] = __builtin_amdgcn_mfma_f32_16x16x32_bf16(af[mt], bfr[nt], acc[mt][nt], 0, 0, 0);
    __builtin_amdgcn_s_setprio(0);
    cur ^= 1;
  }

  const float* bias = (z == 0) ? bq : (z == 1) ? bk : bv;
  const float bsc = (z == 0) ? QSCALE : 1.0f;
  const int rg = kq << 2;
#pragma unroll
  for (int mt = 0; mt < 4; ++mt) {
    const int mb = m0 + wm * 64 + mt * 16 + rg;
    const int b = mb >> 11;
    const int s = mb & 2047;
#pragma unroll
    for (int nt = 0; nt < 4; ++nt) {
      const int n = n0 + wn * 64 + nt * 16 + fr;
      const float bvv = bias[n] * bsc;
      const int h = n >> 6;
      const int d = n & 63;
      if (z == 2) {
        u16x4 pk;
#pragma unroll
        for (int r = 0; r < 4; ++r) pk[r] = f2bf(acc[mt][nt][r] + bvv);
        const int pbase = (s & ~31) | ((s & 12) << 1) | ((s & 16) >> 2);
        *(u16x4*)&Vtb[(((size_t)(b * 16 + h) << 6) + d) * 2048 + pbase] = pk;
      } else {
        unsigned short* O = (z == 0) ? Qb : Kb;
#pragma unroll
        for (int r = 0; r < 4; ++r)
          O[(((size_t)(b * 16 + h) << 11) + s + r) * 64 + d] = f2bf(acc[mt][nt][r] + bvv);
      }
    }
  }
}

// ---------------- flash attention (S^T, no-max softmax, register P) ----------
// r15: full-iteration-ahead staging. r12 waited on SAME-iter loads (V via
// vmcnt(2) ~800cy after issue; K via vmcnt(0) at iter end) -> latency partially
// exposed. Now Vts is also double-buffered (LDS 64KB, still 2 blocks/CU) and
// K_{j+1}+V_{j+1} are issued a FULL iter ahead:
//   barrier (all waves done reading buf[(j-1)&1] -> safe to overwrite)
//   stage j+1 -> buf[(j+1)&1]
//   vmcnt(4) (own j loads landed; j+1's 4 in flight)
//   barrier (ALL waves' j loads landed -- vmcnt is per-wave)
//   compute j (zero memory waits)
// Offsets wrap via (j+1)&15 so the last prefetch restages tile 0 (no OOB).
__global__ __launch_bounds__(512, 4) void k_flash(
    const unsigned short* __restrict__ Qb, const unsigned short* __restrict__ Kb,
    const unsigned short* __restrict__ Vtb, unsigned short* __restrict__ Ctx) {
  __shared__ unsigned short Ks[2 * 128 * 64];   // 32KB dbuf [key][64d], 3-bit chunk xor
  __shared__ unsigned short Vts[2 * 64 * 128];  // 32KB dbuf [d][128k_perm], 4-bit chunk xor
  const int tid = threadIdx.x;
  const int lane = tid & 63;
  const int wq = tid >> 6;           // 0..7
  const int fr = lane & 15;
  const int qd = lane >> 4;
  const int lin = blockIdx.x + (blockIdx.y << 3);        // 0..511
  const int swz = ((lin & 7) << 6) + (lin >> 3);         // chunk 64 per XCD
  const int bh = swz >> 3;                               // 0..63
  const int q0 = (swz & 7) << 8;                         // 0..1792
  const size_t hoff = (size_t)bh << 17;  // 2048*64
  const unsigned short* Qh = Qb + hoff + ((size_t)q0 << 6);

  // ---- staging base addresses (per-iter offset added uniformly) ----
  const unsigned short* kg[2];
  const unsigned short* vg[2];
  unsigned short* kl[2];
  unsigned short* vl[2];
#pragma unroll
  for (int p = 0; p < 2; ++p) {
    int slot = p * 512 + tid;
    int kr = slot >> 3, ch = slot & 7;
    kg[p] = Kb + hoff + (size_t)kr * 64 + ((ch ^ (kr & 7)) << 3);
    kl[p] = Ks + slot * 8;
    int dr = slot >> 4, ch2 = slot & 15;
    vg[p] = Vtb + hoff + (size_t)dr * 2048 + ((ch2 ^ (dr & 15)) << 3);
    vl[p] = Vts + slot * 8;
  }

  // ---- slim LDS read base offsets (kt/dt terms fold to ds_read immediates) ----
  int kbase[2];
#pragma unroll
  for (int ds = 0; ds < 2; ++ds)
    kbase[ds] = fr * 64 + (((ds * 4 + qd) ^ (fr & 7)) << 3);
  int vbase[4];
#pragma unroll
  for (int ks = 0; ks < 4; ++ks)
    vbase[ks] = fr * 128 + (((ks * 4 + qd) ^ fr) << 3);

  // Q fragments: B[n=query][k=d]; row = wq*32+qt*16+fr, d = ds*32+qd*8..+7
  bf16x8 qf[2][2];
#pragma unroll
  for (int qt = 0; qt < 2; ++qt)
#pragma unroll
    for (int ds = 0; ds < 2; ++ds)
      qf[qt][ds] = *(const bf16x8*)&Qh[(wq * 32 + qt * 16 + fr) * 64 + ds * 32 + qd * 8];

  f32x4 zero4 = {0.f, 0.f, 0.f, 0.f};
  f32x4 o_acc[2][4];
  f32x2 l2[2] = {{0.f, 0.f}, {0.f, 0.f}};
#pragma unroll
  for (int mt = 0; mt < 2; ++mt)
#pragma unroll
    for (int dt = 0; dt < 4; ++dt) o_acc[mt][dt] = zero4;

  // ---- prologue: issue K_0,V_0 -> buf0 (no drain; j=0's vmcnt(4) waits) ----
  gload16(kg[0], kl[0]);
  gload16(kg[1], kl[1]);
  gload16(vg[0], vl[0]);
  gload16(vg[1], vl[1]);

  for (int j = 0; j < 16; ++j) {
    // all waves finished reading buf[(j-1)&1] -> safe to overwrite it
    __builtin_amdgcn_s_barrier();
    const int jn = (j + 1) & 15;           // wrap: last iter restages tile 0
    const int sb = ((j + 1) & 1) << 13;    // stage dest buf (8192 el)
    gload16(kg[0] + jn * 8192, kl[0] + sb);
    gload16(kg[1] + jn * 8192, kl[1] + sb);
    gload16(vg[0] + jn * 128, vl[0] + sb);
    gload16(vg[1] + jn * 128, vl[1] + sb);
    // own j-loads (issued last iter) landed; j+1's 4 in flight
    asm volatile("s_waitcnt vmcnt(4)" ::: "memory");
    __builtin_amdgcn_s_barrier();          // ALL waves' j-loads landed

    const int cb = (j & 1) << 13;          // current buf
    const unsigned short* Kc = Ks + cb;

    // ---- fused S^T = K·Q^T -> exp2 -> l-sum -> bf16 pack, per key-pair ----
    u32x4 pfw[2][4];
#pragma unroll
    for (int ks = 0; ks < 4; ++ks) {
      f32x4 st0[2], st1[2];  // [qt] for kt=2ks, 2ks+1
      st0[0] = zero4; st0[1] = zero4; st1[0] = zero4; st1[1] = zero4;
      __builtin_amdgcn_s_setprio(1);
#pragma unroll
      for (int ds = 0; ds < 2; ++ds) {
        bf16x8 kf0 = *(const bf16x8*)&Kc[kbase[ds] + (2 * ks) * 1024];
        bf16x8 kf1 = *(const bf16x8*)&Kc[kbase[ds] + (2 * ks + 1) * 1024];
        st0[0] = __builtin_amdgcn_mfma_f32_16x16x32_bf16(kf0, qf[0][ds], st0[0], 0, 0, 0);
        st0[1] = __builtin_amdgcn_mfma_f32_16x16x32_bf16(kf0, qf[1][ds], st0[1], 0, 0, 0);
        st1[0] = __builtin_amdgcn_mfma_f32_16x16x32_bf16(kf1, qf[0][ds], st1[0], 0, 0, 0);
        st1[1] = __builtin_amdgcn_mfma_f32_16x16x32_bf16(kf1, qf[1][ds], st1[1], 0, 0, 0);
      }
      __builtin_amdgcn_s_setprio(0);
#pragma unroll
      for (int mt = 0; mt < 2; ++mt) {
#pragma unroll
        for (int r = 0; r < 4; ++r) {
          st0[mt][r] = __builtin_amdgcn_exp2f(st0[mt][r]);
          st1[mt][r] = __builtin_amdgcn_exp2f(st1[mt][r]);
        }
        f32x2 s01 = {st0[mt][0], st0[mt][1]};
        f32x2 s23 = {st0[mt][2], st0[mt][3]};
        f32x2 t01 = {st1[mt][0], st1[mt][1]};
        f32x2 t23 = {st1[mt][2], st1[mt][3]};
        l2[mt] += (s01 + s23) + (t01 + t23);
        u32x4 pk;
        pk[0] = cvtpk(st0[mt][0], st0[mt][1]);
        pk[1] = cvtpk(st0[mt][2], st0[mt][3]);
        pk[2] = cvtpk(st1[mt][0], st1[mt][1]);
        pk[3] = cvtpk(st1[mt][2], st1[mt][3]);
        pfw[mt][ks] = pk;
      }
    }

    // ---- O += P · V : A-fragments from packed regs (permuted-key order) ----
    __builtin_amdgcn_s_setprio(1);
#pragma unroll
    for (int ks = 0; ks < 4; ++ks) {
      bf16x8 pf0 = __builtin_bit_cast(bf16x8, pfw[0][ks]);
      bf16x8 pf1 = __builtin_bit_cast(bf16x8, pfw[1][ks]);
#pragma unroll
      for (int dt = 0; dt < 4; ++dt) {
        bf16x8 vf = *(const bf16x8*)&Vts[cb + vbase[ks] + dt * 2048];
        o_acc[0][dt] = __builtin_amdgcn_mfma_f32_16x16x32_bf16(pf0, vf, o_acc[0][dt], 0, 0, 0);
        o_acc[1][dt] = __builtin_amdgcn_mfma_f32_16x16x32_bf16(pf1, vf, o_acc[1][dt], 0, 0, 0);
      }
    }
    __builtin_amdgcn_s_setprio(0);
    // no end-of-iter sync: next iter's top barrier protects buf reuse
  }

  // reduce l across the 4 lanes sharing each query (fr), once
  float l_red[2];
#pragma unroll
  for (int mt = 0; mt < 2; ++mt) {
    float lv = l2[mt][0] + l2[mt][1];
    lv += __shfl_xor(lv, 16);
    lv += __shfl_xor(lv, 32);
    l_red[mt] = lv;
  }

  // epilogue: normalize, write context [b][s][h*64+d] bf16
  const int b = bh >> 4;
  const int h = bh & 15;
#pragma unroll
  for (int mt = 0; mt < 2; ++mt) {
#pragma unroll
    for (int r = 0; r < 4; ++r) {
      float lv = __shfl(l_red[mt], qd * 4 + r);
      float rl = 1.0f / lv;
      int s = q0 + wq * 32 + mt * 16 + qd * 4 + r;
      size_t base = (((size_t)b * 2048 + s) << 10) + (h << 6);
#pragma unroll
      for (int dt = 0; dt < 4; ++dt) Ctx[base + dt * 16 + fr] = f2bf(o_acc[mt][dt][r] * rl);
    }
  }
}

// ---------------- output projection GEMM (f32 out) ----------------
// r13 (unchanged): dbuf pipeline + paired-row XOR swizzle.
__global__ __launch_bounds__(256, 3) void k_gemm_out(
    const unsigned short* __restrict__ Ctx, const unsigned short* __restrict__ Wo,
    const float* __restrict__ bo, float* __restrict__ out) {
  __shared__ unsigned short As[2 * 4096];
  __shared__ unsigned short Bs[2 * 4096];
  const int tid = threadIdx.x;
  const int lane = tid & 63;
  const int w = tid >> 6;
  const int wm = w & 1;
  const int wn = w >> 1;
  const int lin = blockIdx.x + (blockIdx.y << 3);
  const int swz = ((lin & 7) << 6) + (lin >> 3);
  const int m0 = (swz >> 3) << 7;
  const int n0 = (swz & 7) << 7;

  const int sR = tid >> 3;
  const int sc_ = (tid & 7) ^ (sR & 7);
  const int mrow0 = 2 * sR + (sc_ >> 2);
  const int kc0 = (sc_ & 3) << 3;
  const unsigned short* srcA = Ctx + (size_t)(m0 + mrow0) * 1024 + kc0;
  const unsigned short* srcB = Wo + (size_t)(n0 + mrow0) * 1024 + kc0;
  unsigned short* dstA = As + tid * 8;
  unsigned short* dstB = Bs + tid * 8;

  const int fr = lane & 15;
  const int kq = lane >> 4;
  int aoff[4], boff[4];
#pragma unroll
  for (int t = 0; t < 4; ++t) {
    int ra = wm * 64 + t * 16 + fr;
    aoff[t] = ((ra >> 1) << 6) + (((((ra & 1) << 2) + kq) ^ ((ra >> 1) & 7)) << 3);
    int rb = wn * 64 + t * 16 + fr;
    boff[t] = ((rb >> 1) << 6) + (((((rb & 1) << 2) + kq) ^ ((rb >> 1) & 7)) << 3);
  }

  f32x4 zero4 = {0.f, 0.f, 0.f, 0.f};
  f32x4 acc[4][4];
#pragma unroll
  for (int i = 0; i < 4; ++i)
#pragma unroll
    for (int jj = 0; jj < 4; ++jj) acc[i][jj] = zero4;

  gload16(srcA, dstA);
  gload16(srcA + 65536, dstA + 2048);
  gload16(srcB, dstB);
  gload16(srcB + 65536, dstB + 2048);

  int cur = 0;
  for (int kt = 0; kt < 32; ++kt) {
    const int kon = ((kt + 1) & 31) << 5;
    const int soff = (cur ^ 1) << 12;
    gload16(srcA + kon, dstA + soff);
    gload16(srcA + 65536 + kon, dstA + soff + 2048);
    gload16(srcB + kon, dstB + soff);
    gload16(srcB + 65536 + kon, dstB + soff + 2048);

    asm volatile("s_waitcnt vmcnt(4)" ::: "memory");
    __builtin_amdgcn_s_barrier();

    const unsigned short* Ac = As + (cur << 12);
    const unsigned short* Bc = Bs + (cur << 12);
    bf16x8 af[4], bfr[4];
#pragma unroll
    for (int mt = 0; mt < 4; ++mt) af[mt] = *(const bf16x8*)&Ac[aoff[mt]];
#pragma unroll
    for (int nt = 0; nt < 4; ++nt) bfr[nt] = *(const bf16x8*)&Bc[boff[nt]];

    asm volatile("s_waitcnt lgkmcnt(0)" ::: "memory");
    __builtin_amdgcn_s_barrier();

    __builtin_amdgcn_s_setprio(1);
#pragma unroll
    for (int mt = 0; mt < 4; ++mt)
#pragma unroll
      for (int nt = 0; nt < 4; ++nt)
        acc[mt][nt] = __builtin_amdgcn_mfma_f32_16x16x32_bf16(af[mt], bfr[nt], acc[mt][nt], 0, 0, 0);
    __builtin_amdgcn_s_setprio(0);
    cur ^= 1;
  }

  const int rg = kq << 2;
#pragma unroll
  for (int mt = 0; mt < 4; ++mt) {
    const int mb = m0 + wm * 64 + mt * 16 + rg;
#pragma unroll
    for (int nt = 0; nt < 4; ++nt) {
      const int n = n0 + wn * 64 + nt * 16 + fr;
      const float bvv = bo[n];
#pragma unroll
      for (int r = 0; r < 4; ++r)
        out[(size_t)(mb + r) * 1024 + n] = acc[mt][nt][r] + bvv;
    }
  }
}

// ---------------- host ----------------
extern "C" void kernel_launch(void* const* d_in, const int* in_sizes, int n_in,
                              void* d_out, int out_size, void* d_ws, size_t ws_size,
                              hipStream_t stream) {
  (void)in_sizes; (void)n_in; (void)out_size; (void)ws_size;
  const float* x = (const float*)d_in[0];
  const float* Wq = (const float*)d_in[1];
  const float* bq = (const float*)d_in[2];
  const float* Wk = (const float*)d_in[3];
  const float* bk = (const float*)d_in[4];
  const float* Wv = (const float*)d_in[5];
  const float* bv = (const float*)d_in[6];
  const float* Wo = (const float*)d_in[7];
  const float* bo = (const float*)d_in[8];
  float* out = (float*)d_out;

  unsigned short* xb = (unsigned short*)d_ws;  // 8388608 el
  unsigned short* Wb = xb + 8388608;           // 4194304 el (q,k,v,o)
  unsigned short* Qb = Wb + 4194304;           // [b,h,s,d]
  unsigned short* Kb = Qb + 8388608;           // [b,h,s,d]
  unsigned short* Vtb = Kb + 8388608;          // [b,h,d,s_perm]
  unsigned short* Ctx = xb;                    // reuse xb (dead after k_gemm_qkv)

  k_cvt<<<12288, 256, 0, stream>>>(x, Wq, Wk, Wv, Wo, xb, Wb);
  k_gemm_qkv<<<dim3(8, 64, 3), 256, 0, stream>>>(xb, Wb, bq, bk, bv, Qb, Kb, Vtb);
  k_flash<<<dim3(8, 64), 512, 0, stream>>>(Qb, Kb, Vtb, Ctx);
  k_gemm_out<<<dim3(8, 64), 256, 0, stream>>>(Ctx, Wb + 3 * 1048576, bo, out);
}

// Round 9
// 259.520 us; speedup vs baseline: 1.0451x; 1.0063x over previous
//
#include <hip/hip_runtime.h>

// SelfAttention: B=4, S=2048, D=1024, H=16, Hd=64. f32 in/out, bf16 MFMA inside.

#define LOG2E 1.4426950408889634f
#define QSCALE (0.125f * LOG2E)   // 1/sqrt(64) * log2(e), folded into Wq/bq

typedef __bf16 bf16x8 __attribute__((ext_vector_type(8)));
typedef float f32x4 __attribute__((ext_vector_type(4)));
typedef float f32x2 __attribute__((ext_vector_type(2)));
typedef unsigned short u16x4 __attribute__((ext_vector_type(4)));
typedef unsigned short u16x8 __attribute__((ext_vector_type(8)));
typedef unsigned int u32x4 __attribute__((ext_vector_type(4)));

__device__ __forceinline__ unsigned short f2bf(float f) {
  unsigned int u = __builtin_bit_cast(unsigned int, f);
  u += 0x7fffu + ((u >> 16) & 1u);   // RNE
  return (unsigned short)(u >> 16);
}

// single-instruction pack: bf16(a) low16, bf16(b) high16 (RNE). gfx950 only.
__device__ __forceinline__ unsigned int cvtpk(float a, float b) {
  unsigned int r;
  asm("v_cvt_pk_bf16_f32 %0, %1, %2" : "=v"(r) : "v"(a), "v"(b));
  return r;
}

typedef const __attribute__((address_space(1))) void* gptr_t;
typedef __attribute__((address_space(3))) void* lptr_t;
__device__ __forceinline__ void gload16(const void* g, void* l) {
  __builtin_amdgcn_global_load_lds((gptr_t)g, (lptr_t)l, 16, 0, 0);
}

// ---------------- merged convert kernel ----------------
__global__ __launch_bounds__(256) void k_cvt(const float* __restrict__ x,
                                             const float* __restrict__ Wq, const float* __restrict__ Wk,
                                             const float* __restrict__ Wv, const float* __restrict__ Wo,
                                             unsigned short* __restrict__ xb, unsigned short* __restrict__ Wb) {
  int gi = (blockIdx.x * 256 + threadIdx.x) * 4;
  if (gi < 8388608) {
    f32x4 v = *(const f32x4*)(x + gi);
    u16x4 o; o[0] = f2bf(v[0]); o[1] = f2bf(v[1]); o[2] = f2bf(v[2]); o[3] = f2bf(v[3]);
    *(u16x4*)(xb + gi) = o;
  } else {
    int i = gi - 8388608;
    int wsel = i >> 20;
    int loc = i & 1048575;
    const float* src = (wsel == 0) ? Wq : (wsel == 1) ? Wk : (wsel == 2) ? Wv : Wo;
    float sc = (wsel == 0) ? QSCALE : 1.0f;
    f32x4 v = *(const f32x4*)(src + loc);
    u16x4 o; o[0] = f2bf(v[0] * sc); o[1] = f2bf(v[1] * sc); o[2] = f2bf(v[2] * sc); o[3] = f2bf(v[3] * sc);
    *(u16x4*)(Wb + i) = o;
  }
}

// ---------------- QKV projection GEMM ----------------
// r16: swapped-operand epilogue for z<2. WRITE_SIZE showed 66MB vs 48 legit --
// the old z<2 epilogue did 64 scalar 2B stores/thread (d along lanes, s along
// regs). Feeding W as the MFMA *A* operand makes D-rows = W-rows = d, so the 4
// acc regs span consecutive d -> one u16x4 (8B) store per fragment, 16/thread,
// 32B-contiguous runs per s-row; bias becomes a float4 load. K-loop untouched:
// block-uniform pointer swap selects which LDS tile feeds A vs B. z=2 (Vtb
// permuted layout) keeps the original orientation. Same math (transposed).
__global__ __launch_bounds__(256, 3) void k_gemm_qkv(
    const unsigned short* __restrict__ xb, const unsigned short* __restrict__ Wb,
    const float* __restrict__ bq, const float* __restrict__ bk, const float* __restrict__ bv,
    unsigned short* __restrict__ Qb, unsigned short* __restrict__ Kb, unsigned short* __restrict__ Vtb) {
  __shared__ unsigned short As[2 * 4096];  // 16KB: 2 bufs x 64 rows x 128B (paired-row swz)
  __shared__ unsigned short Bs[2 * 4096];
  const int tid = threadIdx.x;
  const int lane = tid & 63;
  const int w = tid >> 6;
  const int wm = w & 1;
  const int wn = w >> 1;
  const int lin = blockIdx.x + (blockIdx.y << 3) + (blockIdx.z << 9);
  const int swz = (lin & 7) * 192 + (lin >> 3);
  const int z = swz >> 9;
  const int m0 = ((swz >> 3) & 63) << 7;
  const int n0 = (swz & 7) << 7;
  const unsigned short* W = Wb + ((size_t)z << 20);

  const int sR = tid >> 3;
  const int sc_ = (tid & 7) ^ (sR & 7);
  const int mrow0 = 2 * sR + (sc_ >> 2);
  const int kc0 = (sc_ & 3) << 3;
  const unsigned short* srcA = xb + (size_t)(m0 + mrow0) * 1024 + kc0;
  const unsigned short* srcB = W + (size_t)(n0 + mrow0) * 1024 + kc0;
  unsigned short* dstA = As + tid * 8;
  unsigned short* dstB = Bs + tid * 8;

  const int fr = lane & 15;
  const int kq = lane >> 4;
  int aoff[4], boff[4];
#pragma unroll
  for (int t = 0; t < 4; ++t) {
    int ra = wm * 64 + t * 16 + fr;
    aoff[t] = ((ra >> 1) << 6) + (((((ra & 1) << 2) + kq) ^ ((ra >> 1) & 7)) << 3);
    int rb = wn * 64 + t * 16 + fr;
    boff[t] = ((rb >> 1) << 6) + (((((rb & 1) << 2) + kq) ^ ((rb >> 1) & 7)) << 3);
  }

  // operand roles: z<2 -> A=W (Bs), B=x (As): D[d][s]. z==2 -> original D[s][d].
  const unsigned short* PA = (z == 2) ? As : Bs;
  const unsigned short* PB = (z == 2) ? Bs : As;

  f32x4 zero4 = {0.f, 0.f, 0.f, 0.f};
  f32x4 acc[4][4];
#pragma unroll
  for (int i = 0; i < 4; ++i)
#pragma unroll
    for (int jj = 0; jj < 4; ++jj) acc[i][jj] = zero4;

  gload16(srcA, dstA);
  gload16(srcA + 65536, dstA + 2048);
  gload16(srcB, dstB);
  gload16(srcB + 65536, dstB + 2048);

  int cur = 0;
  for (int kt = 0; kt < 32; ++kt) {
    const int kon = ((kt + 1) & 31) << 5;
    const int soff = (cur ^ 1) << 12;
    gload16(srcA + kon, dstA + soff);
    gload16(srcA + 65536 + kon, dstA + soff + 2048);
    gload16(srcB + kon, dstB + soff);
    gload16(srcB + 65536 + kon, dstB + soff + 2048);

    asm volatile("s_waitcnt vmcnt(4)" ::: "memory");
    __builtin_amdgcn_s_barrier();

    const unsigned short* Ac = PA + (cur << 12);
    const unsigned short* Bc = PB + (cur << 12);
    bf16x8 af[4], bfr[4];
#pragma unroll
    for (int mt = 0; mt < 4; ++mt) af[mt] = *(const bf16x8*)&Ac[aoff[mt]];
#pragma unroll
    for (int nt = 0; nt < 4; ++nt) bfr[nt] = *(const bf16x8*)&Bc[boff[nt]];

    asm volatile("s_waitcnt lgkmcnt(0)" ::: "memory");
    __builtin_amdgcn_s_barrier();

    __builtin_amdgcn_s_setprio(1);
#pragma unroll
    for (int mt = 0; mt < 4; ++mt)
#pragma unroll
      for (int nt = 0; nt < 4; ++nt)
        acc[mt][nt] = __builtin_amdgcn_mfma_f32_16x16x32_bf16(af[mt], bfr[nt], acc[mt][nt], 0, 0, 0);
    __builtin_amdgcn_s_setprio(0);
    cur ^= 1;
  }

  const float* bias = (z == 0) ? bq : (z == 1) ? bk : bv;
  const float bsc = (z == 0) ? QSCALE : 1.0f;
  const int rg = kq << 2;
  if (z == 2) {
    // original orientation: rows = s (regs), cols = d (fr)
#pragma unroll
    for (int mt = 0; mt < 4; ++mt) {
      const int mb = m0 + wm * 64 + mt * 16 + rg;
      const int b = mb >> 11;
      const int s = mb & 2047;
#pragma unroll
      for (int nt = 0; nt < 4; ++nt) {
        const int n = n0 + wn * 64 + nt * 16 + fr;
        const float bvv = bias[n];
        const int h = n >> 6;
        const int d = n & 63;
        u16x4 pk;
#pragma unroll
        for (int r = 0; r < 4; ++r) pk[r] = f2bf(acc[mt][nt][r] + bvv);
        const int pbase = (s & ~31) | ((s & 12) << 1) | ((s & 16) >> 2);
        *(u16x4*)&Vtb[(((size_t)(b * 16 + h) << 6) + d) * 2048 + pbase] = pk;
      }
    }
  } else {
    // swapped: rows = n (regs, 4 consecutive d), cols = s (fr)
    unsigned short* O = (z == 0) ? Qb : Kb;
#pragma unroll
    for (int mt = 0; mt < 4; ++mt) {
      const int nb = n0 + wm * 64 + mt * 16 + rg;  // n for r=0 (consecutive 4)
      const int h = nb >> 6;
      const int dbase = nb & 63;
      f32x4 bv4 = *(const f32x4*)&bias[nb];
#pragma unroll
      for (int r = 0; r < 4; ++r) bv4[r] *= bsc;
#pragma unroll
      for (int nt = 0; nt < 4; ++nt) {
        const int sb = m0 + wn * 64 + nt * 16 + fr;
        const int b = sb >> 11;
        const int s = sb & 2047;
        u16x4 pk;
#pragma unroll
        for (int r = 0; r < 4; ++r) pk[r] = f2bf(acc[mt][nt][r] + bv4[r]);
        *(u16x4*)&O[(((size_t)(b * 16 + h) << 11) + s) * 64 + dbase] = pk;
      }
    }
  }
}

// ---------------- flash attention (S^T, no-max softmax, register P) ----------
// r15 (unchanged): full-iteration-ahead staging, K+V both double-buffered
// (64KB LDS, 2 blocks/CU); stage j+1 at iter top, vmcnt(4)+barrier, compute j
// with zero memory waits.
__global__ __launch_bounds__(512, 4) void k_flash(
    const unsigned short* __restrict__ Qb, const unsigned short* __restrict__ Kb,
    const unsigned short* __restrict__ Vtb, unsigned short* __restrict__ Ctx) {
  __shared__ unsigned short Ks[2 * 128 * 64];   // 32KB dbuf [key][64d], 3-bit chunk xor
  __shared__ unsigned short Vts[2 * 64 * 128];  // 32KB dbuf [d][128k_perm], 4-bit chunk xor
  const int tid = threadIdx.x;
  const int lane = tid & 63;
  const int wq = tid >> 6;           // 0..7
  const int fr = lane & 15;
  const int qd = lane >> 4;
  const int lin = blockIdx.x + (blockIdx.y << 3);        // 0..511
  const int swz = ((lin & 7) << 6) + (lin >> 3);         // chunk 64 per XCD
  const int bh = swz >> 3;                               // 0..63
  const int q0 = (swz & 7) << 8;                         // 0..1792
  const size_t hoff = (size_t)bh << 17;  // 2048*64
  const unsigned short* Qh = Qb + hoff + ((size_t)q0 << 6);

  const unsigned short* kg[2];
  const unsigned short* vg[2];
  unsigned short* kl[2];
  unsigned short* vl[2];
#pragma unroll
  for (int p = 0; p < 2; ++p) {
    int slot = p * 512 + tid;
    int kr = slot >> 3, ch = slot & 7;
    kg[p] = Kb + hoff + (size_t)kr * 64 + ((ch ^ (kr & 7)) << 3);
    kl[p] = Ks + slot * 8;
    int dr = slot >> 4, ch2 = slot & 15;
    vg[p] = Vtb + hoff + (size_t)dr * 2048 + ((ch2 ^ (dr & 15)) << 3);
    vl[p] = Vts + slot * 8;
  }

  int kbase[2];
#pragma unroll
  for (int ds = 0; ds < 2; ++ds)
    kbase[ds] = fr * 64 + (((ds * 4 + qd) ^ (fr & 7)) << 3);
  int vbase[4];
#pragma unroll
  for (int ks = 0; ks < 4; ++ks)
    vbase[ks] = fr * 128 + (((ks * 4 + qd) ^ fr) << 3);

  bf16x8 qf[2][2];
#pragma unroll
  for (int qt = 0; qt < 2; ++qt)
#pragma unroll
    for (int ds = 0; ds < 2; ++ds)
      qf[qt][ds] = *(const bf16x8*)&Qh[(wq * 32 + qt * 16 + fr) * 64 + ds * 32 + qd * 8];

  f32x4 zero4 = {0.f, 0.f, 0.f, 0.f};
  f32x4 o_acc[2][4];
  f32x2 l2[2] = {{0.f, 0.f}, {0.f, 0.f}};
#pragma unroll
  for (int mt = 0; mt < 2; ++mt)
#pragma unroll
    for (int dt = 0; dt < 4; ++dt) o_acc[mt][dt] = zero4;

  // prologue: issue K_0,V_0 -> buf0 (no drain; j=0's vmcnt(4) waits)
  gload16(kg[0], kl[0]);
  gload16(kg[1], kl[1]);
  gload16(vg[0], vl[0]);
  gload16(vg[1], vl[1]);

  for (int j = 0; j < 16; ++j) {
    __builtin_amdgcn_s_barrier();          // buf[(j-1)&1] free
    const int jn = (j + 1) & 15;
    const int sb = ((j + 1) & 1) << 13;
    gload16(kg[0] + jn * 8192, kl[0] + sb);
    gload16(kg[1] + jn * 8192, kl[1] + sb);
    gload16(vg[0] + jn * 128, vl[0] + sb);
    gload16(vg[1] + jn * 128, vl[1] + sb);
    asm volatile("s_waitcnt vmcnt(4)" ::: "memory");
    __builtin_amdgcn_s_barrier();          // ALL waves' j-loads landed

    const int cb = (j & 1) << 13;
    const unsigned short* Kc = Ks + cb;

    u32x4 pfw[2][4];
#pragma unroll
    for (int ks = 0; ks < 4; ++ks) {
      f32x4 st0[2], st1[2];
      st0[0] = zero4; st0[1] = zero4; st1[0] = zero4; st1[1] = zero4;
      __builtin_amdgcn_s_setprio(1);
#pragma unroll
      for (int ds = 0; ds < 2; ++ds) {
        bf16x8 kf0 = *(const bf16x8*)&Kc[kbase[ds] + (2 * ks) * 1024];
        bf16x8 kf1 = *(const bf16x8*)&Kc[kbase[ds] + (2 * ks + 1) * 1024];
        st0[0] = __builtin_amdgcn_mfma_f32_16x16x32_bf16(kf0, qf[0][ds], st0[0], 0, 0, 0);
        st0[1] = __builtin_amdgcn_mfma_f32_16x16x32_bf16(kf0, qf[1][ds], st0[1], 0, 0, 0);
        st1[0] = __builtin_amdgcn_mfma_f32_16x16x32_bf16(kf1, qf[0][ds], st1[0], 0, 0, 0);
        st1[1] = __builtin_amdgcn_mfma_f32_16x16x32_bf16(kf1, qf[1][ds], st1[1], 0, 0, 0);
      }
      __builtin_amdgcn_s_setprio(0);
#pragma unroll
      for (int mt = 0; mt < 2; ++mt) {
#pragma unroll
        for (int r = 0; r < 4; ++r) {
          st0[mt][r] = __builtin_amdgcn_exp2f(st0[mt][r]);
          st1[mt][r] = __builtin_amdgcn_exp2f(st1[mt][r]);
        }
        f32x2 s01 = {st0[mt][0], st0[mt][1]};
        f32x2 s23 = {st0[mt][2], st0[mt][3]};
        f32x2 t01 = {st1[mt][0], st1[mt][1]};
        f32x2 t23 = {st1[mt][2], st1[mt][3]};
        l2[mt] += (s01 + s23) + (t01 + t23);
        u32x4 pk;
        pk[0] = cvtpk(st0[mt][0], st0[mt][1]);
        pk[1] = cvtpk(st0[mt][2], st0[mt][3]);
        pk[2] = cvtpk(st1[mt][0], st1[mt][1]);
        pk[3] = cvtpk(st1[mt][2], st1[mt][3]);
        pfw[mt][ks] = pk;
      }
    }

    __builtin_amdgcn_s_setprio(1);
#pragma unroll
    for (int ks = 0; ks < 4; ++ks) {
      bf16x8 pf0 = __builtin_bit_cast(bf16x8, pfw[0][ks]);
      bf16x8 pf1 = __builtin_bit_cast(bf16x8, pfw[1][ks]);
#pragma unroll
      for (int dt = 0; dt < 4; ++dt) {
        bf16x8 vf = *(const bf16x8*)&Vts[cb + vbase[ks] + dt * 2048];
        o_acc[0][dt] = __builtin_amdgcn_mfma_f32_16x16x32_bf16(pf0, vf, o_acc[0][dt], 0, 0, 0);
        o_acc[1][dt] = __builtin_amdgcn_mfma_f32_16x16x32_bf16(pf1, vf, o_acc[1][dt], 0, 0, 0);
      }
    }
    __builtin_amdgcn_s_setprio(0);
  }

  float l_red[2];
#pragma unroll
  for (int mt = 0; mt < 2; ++mt) {
    float lv = l2[mt][0] + l2[mt][1];
    lv += __shfl_xor(lv, 16);
    lv += __shfl_xor(lv, 32);
    l_red[mt] = lv;
  }

  const int b = bh >> 4;
  const int h = bh & 15;
#pragma unroll
  for (int mt = 0; mt < 2; ++mt) {
#pragma unroll
    for (int r = 0; r < 4; ++r) {
      float lv = __shfl(l_red[mt], qd * 4 + r);
      float rl = 1.0f / lv;
      int s = q0 + wq * 32 + mt * 16 + qd * 4 + r;
      size_t base = (((size_t)b * 2048 + s) << 10) + (h << 6);
#pragma unroll
      for (int dt = 0; dt < 4; ++dt) Ctx[base + dt * 16 + fr] = f2bf(o_acc[mt][dt][r] * rl);
    }
  }
}

// ---------------- output projection GEMM (f32 out) ----------------
// r16: swapped operands (A=Wo, B=Ctx): acc regs span consecutive n -> f32x4
// stores (16 dwordx4 vs 64 dword) + float4 bias. K-loop/swizzle unchanged.
__global__ __launch_bounds__(256, 3) void k_gemm_out(
    const unsigned short* __restrict__ Ctx, const unsigned short* __restrict__ Wo,
    const float* __restrict__ bo, float* __restrict__ out) {
  __shared__ unsigned short As[2 * 4096];
  __shared__ unsigned short Bs[2 * 4096];
  const int tid = threadIdx.x;
  const int lane = tid & 63;
  const int w = tid >> 6;
  const int wm = w & 1;
  const int wn = w >> 1;
  const int lin = blockIdx.x + (blockIdx.y << 3);
  const int swz = ((lin & 7) << 6) + (lin >> 3);
  const int m0 = (swz >> 3) << 7;
  const int n0 = (swz & 7) << 7;

  const int sR = tid >> 3;
  const int sc_ = (tid & 7) ^ (sR & 7);
  const int mrow0 = 2 * sR + (sc_ >> 2);
  const int kc0 = (sc_ & 3) << 3;
  const unsigned short* srcA = Ctx + (size_t)(m0 + mrow0) * 1024 + kc0;
  const unsigned short* srcB = Wo + (size_t)(n0 + mrow0) * 1024 + kc0;
  unsigned short* dstA = As + tid * 8;
  unsigned short* dstB = Bs + tid * 8;

  const int fr = lane & 15;
  const int kq = lane >> 4;
  int aoff[4], boff[4];
#pragma unroll
  for (int t = 0; t < 4; ++t) {
    int ra = wm * 64 + t * 16 + fr;
    aoff[t] = ((ra >> 1) << 6) + (((((ra & 1) << 2) + kq) ^ ((ra >> 1) & 7)) << 3);
    int rb = wn * 64 + t * 16 + fr;
    boff[t] = ((rb >> 1) << 6) + (((((rb & 1) << 2) + kq) ^ ((rb >> 1) & 7)) << 3);
  }

  f32x4 zero4 = {0.f, 0.f, 0.f, 0.f};
  f32x4 acc[4][4];
#pragma unroll
  for (int i = 0; i < 4; ++i)
#pragma unroll
    for (int jj = 0; jj < 4; ++jj) acc[i][jj] = zero4;

  gload16(srcA, dstA);
  gload16(srcA + 65536, dstA + 2048);
  gload16(srcB, dstB);
  gload16(srcB + 65536, dstB + 2048);

  int cur = 0;
  for (int kt = 0; kt < 32; ++kt) {
    const int kon = ((kt + 1) & 31) << 5;
    const int soff = (cur ^ 1) << 12;
    gload16(srcA + kon, dstA + soff);
    gload16(srcA + 65536 + kon, dstA + soff + 2048);
    gload16(srcB + kon, dstB + soff);
    gload16(srcB + 65536 + kon, dstB + soff + 2048);

    asm volatile("s_waitcnt vmcnt(4)" ::: "memory");
    __builtin_amdgcn_s_barrier();

    // swapped: A-operand from Bs (Wo), B-operand from As (Ctx)
    const unsigned short* Ac = Bs + (cur << 12);
    const unsigned short* Bc = As + (cur << 12);
    bf16x8 af[4], bfr[4];
#pragma unroll
    for (int mt = 0; mt < 4; ++mt) af[mt] = *(const bf16x8*)&Ac[aoff[mt]];
#pragma unroll
    for (int nt = 0; nt < 4; ++nt) bfr[nt] = *(const bf16x8*)&Bc[boff[nt]];

    asm volatile("s_waitcnt lgkmcnt(0)" ::: "memory");
    __builtin_amdgcn_s_barrier();

    __builtin_amdgcn_s_setprio(1);
#pragma unroll
    for (int mt = 0; mt < 4; ++mt)
#pragma unroll
      for (int nt = 0; nt < 4; ++nt)
        acc[mt][nt] = __builtin_amdgcn_mfma_f32_16x16x32_bf16(af[mt], bfr[nt], acc[mt][nt], 0, 0, 0);
    __builtin_amdgcn_s_setprio(0);
    cur ^= 1;
  }

  const int rg = kq << 2;
#pragma unroll
  for (int mt = 0; mt < 4; ++mt) {
    const int nb = n0 + wm * 64 + mt * 16 + rg;  // n for r=0 (consecutive 4)
    const f32x4 bv4 = *(const f32x4*)&bo[nb];
#pragma unroll
    for (int nt = 0; nt < 4; ++nt) {
      const int sb = m0 + wn * 64 + nt * 16 + fr;
      f32x4 o = acc[mt][nt] + bv4;
      *(f32x4*)&out[(size_t)sb * 1024 + nb] = o;
    }
  }
}

// ---------------- host ----------------
extern "C" void kernel_launch(void* const* d_in, const int* in_sizes, int n_in,
                              void* d_out, int out_size, void* d_ws, size_t ws_size,
                              hipStream_t stream) {
  (void)in_sizes; (void)n_in; (void)out_size; (void)ws_size;
  const float* x = (const float*)d_in[0];
  const float* Wq = (const float*)d_in[1];
  const float* bq = (const float*)d_in[2];
  const float* Wk = (const float*)d_in[3];
  const float* bk = (const float*)d_in[4];
  const float* Wv = (const float*)d_in[5];
  const float* bv = (const float*)d_in[6];
  const float* Wo = (const float*)d_in[7];
  const float* bo = (const float*)d_in[8];
  float* out = (float*)d_out;

  unsigned short* xb = (unsigned short*)d_ws;  // 8388608 el
  unsigned short* Wb = xb + 8388608;           // 4194304 el (q,k,v,o)
  unsigned short* Qb = Wb + 4194304;           // [b,h,s,d]
  unsigned short* Kb = Qb + 8388608;           // [b,h,s,d]
  unsigned short* Vtb = Kb + 8388608;          // [b,h,d,s_perm]
  unsigned short* Ctx = xb;                    // reuse xb (dead after k_gemm_qkv)

  k_cvt<<<12288, 256, 0, stream>>>(x, Wq, Wk, Wv, Wo, xb, Wb);
  k_gemm_qkv<<<dim3(8, 64, 3), 256, 0, stream>>>(xb, Wb, bq, bk, bv, Qb, Kb, Vtb);
  k_flash<<<dim3(8, 64), 512, 0, stream>>>(Qb, Kb, Vtb, Ctx);
  k_gemm_out<<<dim3(8, 64), 256, 0, stream>>>(Ctx, Wb + 3 * 1048576, bo, out);
}